// Round 7
// baseline (166.447 us; speedup 1.0000x reference)
//
#include <hip/hip_runtime.h>
#include <math.h>

#define EDIM 128
#define NHEAD 16
#define HDIM 8
#define SEQ 2048
#define BATCH 4
#define NROW (BATCH*SEQ)            // 8192
// -scale*log2(e): folded into Q at projection time so sigmoid = rcp(1+exp2(dot))
#define QNEG (-0.35355339059327373f * 1.4426950408889634f)

#if __has_builtin(__builtin_amdgcn_exp2f)
#define EXP2F(x) __builtin_amdgcn_exp2f(x)
#else
#define EXP2F(x) exp2f(x)
#endif
#define RCPF(x) __builtin_amdgcn_rcpf(x)

typedef __attribute__((ext_vector_type(8))) short short8v;
typedef __attribute__((ext_vector_type(4))) short short4v;
typedef __attribute__((ext_vector_type(4))) float float4v;

union U16x8 { uint4 u; short8v s; };
union U16x4 { uint2 u; short4v s; };

#if __has_builtin(__builtin_amdgcn_mfma_f32_16x16x16bf16_1k)
#define MFMA_PV(a,b,c) __builtin_amdgcn_mfma_f32_16x16x16bf16_1k(a,b,c,0,0,0)
#else
static __device__ __forceinline__ float4v mfma_pv_asm(short4v a, short4v b, float4v c) {
  float4v d;
  asm("v_mfma_f32_16x16x16_bf16 %0, %1, %2, %3" : "=v"(d) : "v"(a), "v"(b), "v"(c));
  return d;
}
#define MFMA_PV(a,b,c) mfma_pv_asm(a,b,c)
#endif

// pack two floats to bf16x2, round-to-nearest-even (values finite)
__device__ __forceinline__ unsigned pk_bf16(float a, float b) {
  unsigned ua = __float_as_uint(a), ub = __float_as_uint(b);
  unsigned lo = (ua + 0x7fffu + ((ua >> 16) & 1u)) >> 16;
  unsigned hi = (ub + 0x7fffu + ((ub >> 16) & 1u)) & 0xffff0000u;
  return lo | hi;
}
__device__ __forceinline__ unsigned short pk_bf16_1(float a) {
  unsigned ua = __float_as_uint(a);
  return (unsigned short)((ua + 0x7fffu + ((ua >> 16) & 1u)) >> 16);
}

// ---------------------------------------------------------------------------
// Transpose the 4 weight matrices W[j][i] -> WT[i][j].
// ---------------------------------------------------------------------------
__global__ __launch_bounds__(256)
void transpose4_kernel(const float* __restrict__ W0, const float* __restrict__ W1,
                       const float* __restrict__ W2, const float* __restrict__ W3,
                       float* __restrict__ WT)
{
  const float* W = (blockIdx.y == 0) ? W0 : (blockIdx.y == 1) ? W1
                 : (blockIdx.y == 2) ? W2 : W3;
  float* out = WT + blockIdx.y * EDIM * EDIM;
  const int i0 = blockIdx.x * 16;
  #pragma unroll
  for (int it = 0; it < 8; ++it) {
    int f = threadIdx.x + it * 256;
    int i = i0 + (f >> 7);
    int j = f & 127;
    out[i * EDIM + j] = W[j * EDIM + i];
  }
}

// ---------------------------------------------------------------------------
// Vt global: [bh][d 0..8][2048] bf16. Fill row d=8 with 1.0 (denominator
// column for the PV MFMA).
// ---------------------------------------------------------------------------
__global__ __launch_bounds__(256)
void ones_kernel(unsigned* __restrict__ Vtg)
{
  unsigned* row = Vtg + ((size_t)blockIdx.x * 9 + 8) * 1024;
  #pragma unroll
  for (int it = 0; it < 4; ++it) row[threadIdx.x + it * 256] = 0x3F803F80u;
}

// ---------------------------------------------------------------------------
// out = X @ W^T + b with pre-transposed WT. 32 rows x 128 cols per block.
// mode 0: Q scaled by QNEG -> bf16 [bh][s][8]
// mode 1: K -> bf16 [bh][s][8]
// mode 2: V -> bf16 Vt[bh][d][s]  (transposed scatter; row 8 = ones)
// mode 3: fp32 row-major [rows][128] (final output)
// ---------------------------------------------------------------------------
__device__ __forceinline__
void proj_body(const float* __restrict__ X, const float* __restrict__ WT,
               const float* __restrict__ bias, void* __restrict__ out, int mode)
{
  __shared__ float xs[32][EDIM];                  // 16 KB
  const int tid = threadIdx.x;
  const int row0 = blockIdx.x * 32;

  const float4* src = (const float4*)(X + row0 * EDIM);
  float4* dst = (float4*)(&xs[0][0]);
  #pragma unroll
  for (int t = 0; t < 4; ++t) dst[tid + t * 256] = src[tid + t * 256];
  __syncthreads();

  const int tc = tid & 31;
  const int tr = tid >> 5;                        // 0..7 (4 rows each)
  const int col0 = tc * 4;

  float acc[4][4];
  #pragma unroll
  for (int r = 0; r < 4; ++r)
    #pragma unroll
    for (int c = 0; c < 4; ++c) acc[r][c] = 0.f;

  #pragma unroll 2
  for (int ib = 0; ib < EDIM / 4; ++ib) {
    const float4 w0 = *(const float4*)(WT + (4 * ib + 0) * EDIM + col0);
    const float4 w1 = *(const float4*)(WT + (4 * ib + 1) * EDIM + col0);
    const float4 w2 = *(const float4*)(WT + (4 * ib + 2) * EDIM + col0);
    const float4 w3 = *(const float4*)(WT + (4 * ib + 3) * EDIM + col0);
    #pragma unroll
    for (int r = 0; r < 4; ++r) {
      const float4 x4 = *(const float4*)(&xs[tr * 4 + r][ib * 4]);  // b128 broadcast
      acc[r][0] += x4.x * w0.x + x4.y * w1.x + x4.z * w2.x + x4.w * w3.x;
      acc[r][1] += x4.x * w0.y + x4.y * w1.y + x4.z * w2.y + x4.w * w3.y;
      acc[r][2] += x4.x * w0.z + x4.y * w1.z + x4.z * w2.z + x4.w * w3.z;
      acc[r][3] += x4.x * w0.w + x4.y * w1.w + x4.z * w2.w + x4.w * w3.w;
    }
  }

  const float4 b4 = *(const float4*)(bias + col0);
  #pragma unroll
  for (int r = 0; r < 4; ++r) {
    const int grow = row0 + tr * 4 + r;
    const float4 o = make_float4(acc[r][0] + b4.x, acc[r][1] + b4.y,
                                 acc[r][2] + b4.z, acc[r][3] + b4.w);
    if (mode == 3) {
      *(float4*)((float*)out + (size_t)grow * EDIM + col0) = o;
    } else {
      const int b = grow >> 11, s = grow & (SEQ - 1);
      const int h = col0 >> 3, d0 = col0 & 7;     // d0 in {0,4}
      const size_t bhs = (size_t)(b * NHEAD + h) * SEQ + s;
      if (mode == 0) {
        uint2 p;
        p.x = pk_bf16(o.x * QNEG, o.y * QNEG);
        p.y = pk_bf16(o.z * QNEG, o.w * QNEG);
        *(uint2*)((unsigned*)out + bhs * 4 + (d0 >> 1)) = p;
      } else if (mode == 1) {
        uint2 p;
        p.x = pk_bf16(o.x, o.y);
        p.y = pk_bf16(o.z, o.w);
        *(uint2*)((unsigned*)out + bhs * 4 + (d0 >> 1)) = p;
      } else {
        unsigned short* vt = (unsigned short*)out;
        const size_t base = (size_t)(b * NHEAD + h) * 9;
        const float oo[4] = {o.x, o.y, o.z, o.w};
        #pragma unroll
        for (int c = 0; c < 4; ++c)
          vt[(base + d0 + c) * SEQ + s] = pk_bf16_1(oo[c]);
      }
    }
  }
}

__global__ __launch_bounds__(256)
void qkv_kernel(const float* __restrict__ X, const float* __restrict__ WT,
                const float* __restrict__ bq, const float* __restrict__ bk,
                const float* __restrict__ bv,
                unsigned* __restrict__ qb, unsigned* __restrict__ kb,
                unsigned* __restrict__ vtg)
{
  const int m = blockIdx.y;
  const float* wt   = WT + m * EDIM * EDIM;
  const float* bias = (m == 0) ? bq : (m == 1) ? bk : bv;
  void* out         = (m == 0) ? (void*)qb : (m == 1) ? (void*)kb : (void*)vtg;
  proj_body(X, wt, bias, out, m);
}

__global__ __launch_bounds__(256)
void oproj_kernel(const float* __restrict__ A, const float* __restrict__ WTo,
                  const float* __restrict__ bo, float* __restrict__ out)
{
  proj_body(A, WTo, bo, (void*)out, 3);
}

// ---------------------------------------------------------------------------
// One 16q x 16k MFMA step.
// S^T = mfma_16x16x32_bf16(A=K-rows, B=Q-frag) -> C[key][q] (row=4*quad+reg,
// col=laneq). Sigmoid elementwise; C-layout of S^T IS the B-layout of
// mfma_16x16x16 (k=4*quad+j, n=laneq) -> PV with NO transform:
// out^T += mfma_16x16x16_bf16(A=Vt-frag [d][key], B=P^T).
// ---------------------------------------------------------------------------
template<bool DIAG>
__device__ __forceinline__
float4v attn_step(short8v kf, short8v qf, short4v vf, float4v acc,
                  int laneq, int quad)
{
  const float4v z = {0.f, 0.f, 0.f, 0.f};
  float4v st = __builtin_amdgcn_mfma_f32_16x16x32_bf16(kf, qf, z, 0, 0, 0);
  unsigned rb[4];
  #pragma unroll
  for (int r = 0; r < 4; ++r) {
    float s = RCPF(1.f + EXP2F(st[r]));           // Q carries -scale*log2e
    if (DIAG) s = (4 * quad + r <= laneq) ? s : 0.f;  // exact: sigma(-1e9)==0
    rb[r] = __float_as_uint(s) + 0x8000u;         // round-half-up to bf16
  }
  U16x4 p;
  p.u.x = __builtin_amdgcn_perm(rb[1], rb[0], 0x07060302u);
  p.u.y = __builtin_amdgcn_perm(rb[3], rb[2], 0x07060302u);
  return MFMA_PV(vf, p.s, acc);
}

// ---------------------------------------------------------------------------
// Causal sigmoid-attention v7: zero-LDS, global/L2 fragment loads.
// Wave = fold-pair of q-tiles (L=g, H=127-g): exactly 129 steps per wave ->
// perfect balance. Block = 4 independent waves (g = 4*(bi>>6)+w), 256 thr,
// no barriers, no LDS -> 8 blocks/CU = 32 waves/CU. Fragments loaded
// directly from L2 (per-XCD working set ~550 KB): K-frag = broadcast
// dwordx4 (256 B/wave), Vt-frag = broadcast dwordx2. Manual 1-deep prefetch
// + unroll 4 keeps 4-8 loads in flight per wave.
// blockIdx low 6 bits = bh -> XCD = bh%8 (L2 locality).
// ---------------------------------------------------------------------------
__global__ __launch_bounds__(256, 8)
void attn_kernel(const unsigned* __restrict__ Qb, const unsigned* __restrict__ Kb,
                 const unsigned* __restrict__ Vtg, float* __restrict__ out)
{
  const int bi    = blockIdx.x;
  const int bh    = bi & 63;
  const int w     = threadIdx.x >> 6;
  const int lane  = threadIdx.x & 63;
  const int laneq = lane & 15;
  const int quad  = lane >> 4;
  const int g     = 4 * (bi >> 6) + w;            // 0..63
  const int L = g, H = 127 - g;                   // q-tile indices (L < H)

  const uint4* Kg = (const uint4*)Kb + (size_t)bh * 2048;
  const uint4* Qg = (const uint4*)Qb + (size_t)bh * 2048;
  const int vrow = (laneq < 8) ? laneq : 8;       // d; rows 9..15 read ones
  const unsigned short* Vt = (const unsigned short*)Vtg
                           + ((size_t)bh * 9 + vrow) * SEQ + 4 * quad;

  // Q B-frags: zero lanes>=16 (pads the K=32 contraction; K-frag quads 1..3
  // hold duplicated data but multiply by these zeros)
  U16x8 qfl, qfh;
  {
    const uint4 rl = Qg[16 * L + laneq];
    const uint4 rh = Qg[16 * H + laneq];
    qfl.u = (lane < 16) ? rl : make_uint4(0u, 0u, 0u, 0u);
    qfh.u = (lane < 16) ? rh : make_uint4(0u, 0u, 0u, 0u);
  }

  float4v accL = {0.f, 0.f, 0.f, 0.f};
  float4v accH = {0.f, 0.f, 0.f, 0.f};

  U16x8 kf; kf.u = Kg[laneq];                     // prefetch t=0
  U16x4 vf; vf.u = *(const uint2*)(Vt);

  // phase A: t = 0..L-1, dual-tile (shared fragments), no diag
  #pragma unroll 4
  for (int t = 0; t < L; ++t) {
    U16x8 kn; kn.u = Kg[16 * (t + 1) + laneq];
    U16x4 vn; vn.u = *(const uint2*)(Vt + 16 * (t + 1));
    accL = attn_step<false>(kf.s, qfl.s, vf.s, accL, laneq, quad);
    accH = attn_step<false>(kf.s, qfh.s, vf.s, accH, laneq, quad);
    kf = kn; vf = vn;
  }
  // t = L: diag for L, normal for H  (prefetch t=L+1; L+1 <= H <= 127)
  {
    U16x8 kn; kn.u = Kg[16 * (L + 1) + laneq];
    U16x4 vn; vn.u = *(const uint2*)(Vt + 16 * (L + 1));
    accL = attn_step<true >(kf.s, qfl.s, vf.s, accL, laneq, quad);
    accH = attn_step<false>(kf.s, qfh.s, vf.s, accH, laneq, quad);
    kf = kn; vf = vn;
  }
  // phase B: t = L+1..H-1, single-tile
  #pragma unroll 4
  for (int t = L + 1; t < H; ++t) {
    U16x8 kn; kn.u = Kg[16 * (t + 1) + laneq];
    U16x4 vn; vn.u = *(const uint2*)(Vt + 16 * (t + 1));
    accH = attn_step<false>(kf.s, qfh.s, vf.s, accH, laneq, quad);
    kf = kn; vf = vn;
  }
  // t = H: diag
  accH = attn_step<true>(kf.s, qfh.s, vf.s, accH, laneq, quad);

  // epilogue: den = acc row 8 (quad 2, reg 0); normalize, store out[q][d]
  const int b_ = bh >> 4, h = bh & 15;
  {
    const int di = __builtin_amdgcn_ds_bpermute((32 + laneq) << 2,
                                                __float_as_int(accL[0]));
    const float inv = RCPF(__int_as_float(di));
    if (lane < 32) {
      const float4 o = make_float4(accL[0] * inv, accL[1] * inv,
                                   accL[2] * inv, accL[3] * inv);
      const int row = 16 * L + laneq;
      *(float4*)(out + ((size_t)(b_ * SEQ + row)) * EDIM + h * HDIM + 4 * quad) = o;
    }
  }
  {
    const int di = __builtin_amdgcn_ds_bpermute((32 + laneq) << 2,
                                                __float_as_int(accH[0]));
    const float inv = RCPF(__int_as_float(di));
    if (lane < 32) {
      const float4 o = make_float4(accH[0] * inv, accH[1] * inv,
                                   accH[2] * inv, accH[3] * inv);
      const int row = 16 * H + laneq;
      *(float4*)(out + ((size_t)(b_ * SEQ + row)) * EDIM + h * HDIM + 4 * quad) = o;
    }
  }
}

// ---------------------------------------------------------------------------
extern "C" void kernel_launch(void* const* d_in, const int* in_sizes, int n_in,
                              void* d_out, int out_size, void* d_ws, size_t ws_size,
                              hipStream_t stream)
{
  const float* x  = (const float*)d_in[0];
  const float* Wq = (const float*)d_in[1];
  const float* bq = (const float*)d_in[2];
  const float* Wk = (const float*)d_in[3];
  const float* bk = (const float*)d_in[4];
  const float* Wv = (const float*)d_in[5];
  const float* bv = (const float*)d_in[6];
  const float* Wo = (const float*)d_in[7];
  const float* bo = (const float*)d_in[8];

  float* ws = (float*)d_ws;
  // layout: WT 65536 f | attn 1048576 f | Qb 524288 dw | Kb 524288 dw | Vtg 589824 dw
  float*    WT   = ws;
  float*    attn = ws + 65536;
  unsigned* Qb   = (unsigned*)(ws + 65536 + 1048576);
  unsigned* Kb   = Qb + (size_t)524288;
  unsigned* Vtg  = Kb + (size_t)524288;

  transpose4_kernel<<<dim3(8, 4), 256, 0, stream>>>(Wq, Wk, Wv, Wo, WT);
  ones_kernel<<<dim3(64), 256, 0, stream>>>(Vtg);
  qkv_kernel<<<dim3(NROW / 32, 3), 256, 0, stream>>>(x, WT, bq, bk, bv, Qb, Kb, Vtg);
  attn_kernel<<<dim3(1024), 256, 0, stream>>>(Qb, Kb, Vtg, attn);
  oproj_kernel<<<dim3(NROW / 32), 256, 0, stream>>>(attn, WT + 3 * EDIM * EDIM, bo,
                                                    (float*)d_out);
}

// Round 9
// 158.346 us; speedup vs baseline: 1.0512x; 1.0512x over previous
//
#include <hip/hip_runtime.h>
#include <math.h>

#define EDIM 128
#define NHEAD 16
#define HDIM 8
#define SEQ 2048
#define BATCH 4
#define NROW (BATCH*SEQ)            // 8192
// -scale*log2(e): folded into Q at projection time so sigmoid = rcp(1+exp2(dot))
#define QNEG (-0.35355339059327373f * 1.4426950408889634f)

#if __has_builtin(__builtin_amdgcn_exp2f)
#define EXP2F(x) __builtin_amdgcn_exp2f(x)
#else
#define EXP2F(x) exp2f(x)
#endif
#define RCPF(x) __builtin_amdgcn_rcpf(x)

typedef __attribute__((ext_vector_type(8))) short short8v;
typedef __attribute__((ext_vector_type(4))) short short4v;
typedef __attribute__((ext_vector_type(4))) float float4v;

union U16x8 { uint4 u; short8v s; };
union U16x4 { uint2 u; short4v s; };

#if __has_builtin(__builtin_amdgcn_mfma_f32_16x16x16bf16_1k)
#define MFMA_PV(a,b,c) __builtin_amdgcn_mfma_f32_16x16x16bf16_1k(a,b,c,0,0,0)
#else
static __device__ __forceinline__ float4v mfma_pv_asm(short4v a, short4v b, float4v c) {
  float4v d;
  asm("v_mfma_f32_16x16x16_bf16 %0, %1, %2, %3" : "=v"(d) : "v"(a), "v"(b), "v"(c));
  return d;
}
#define MFMA_PV(a,b,c) mfma_pv_asm(a,b,c)
#endif

// pack two floats to bf16x2, round-to-nearest-even (values finite)
__device__ __forceinline__ unsigned pk_bf16(float a, float b) {
  unsigned ua = __float_as_uint(a), ub = __float_as_uint(b);
  unsigned lo = (ua + 0x7fffu + ((ua >> 16) & 1u)) >> 16;
  unsigned hi = (ub + 0x7fffu + ((ub >> 16) & 1u)) & 0xffff0000u;
  return lo | hi;
}

// ---------------------------------------------------------------------------
// Transpose the 4 weight matrices W[j][i] -> WT[i][j].
// ---------------------------------------------------------------------------
__global__ __launch_bounds__(256)
void transpose4_kernel(const float* __restrict__ W0, const float* __restrict__ W1,
                       const float* __restrict__ W2, const float* __restrict__ W3,
                       float* __restrict__ WT)
{
  const float* W = (blockIdx.y == 0) ? W0 : (blockIdx.y == 1) ? W1
                 : (blockIdx.y == 2) ? W2 : W3;
  float* out = WT + blockIdx.y * EDIM * EDIM;
  const int i0 = blockIdx.x * 16;
  #pragma unroll
  for (int it = 0; it < 8; ++it) {
    int f = threadIdx.x + it * 256;
    int i = i0 + (f >> 7);
    int j = f & 127;
    out[i * EDIM + j] = W[j * EDIM + i];
  }
}

// ---------------------------------------------------------------------------
// out = X @ W^T + b with pre-transposed WT. 32 rows x 128 cols per block.
// mode 0: Q scaled by QNEG -> bf16 [bh][s][8]
// mode 1/2: K / V -> bf16 [bh][s][8]  (coalesced uint2 stores)
// mode 3: fp32 row-major [rows][128] (final output)
// ---------------------------------------------------------------------------
__device__ __forceinline__
void proj_body(const float* __restrict__ X, const float* __restrict__ WT,
               const float* __restrict__ bias, void* __restrict__ out, int mode)
{
  __shared__ float xs[32][EDIM];                  // 16 KB
  const int tid = threadIdx.x;
  const int row0 = blockIdx.x * 32;

  const float4* src = (const float4*)(X + row0 * EDIM);
  float4* dst = (float4*)(&xs[0][0]);
  #pragma unroll
  for (int t = 0; t < 4; ++t) dst[tid + t * 256] = src[tid + t * 256];
  __syncthreads();

  const int tc = tid & 31;
  const int tr = tid >> 5;                        // 0..7 (4 rows each)
  const int col0 = tc * 4;

  float acc[4][4];
  #pragma unroll
  for (int r = 0; r < 4; ++r)
    #pragma unroll
    for (int c = 0; c < 4; ++c) acc[r][c] = 0.f;

  #pragma unroll 2
  for (int ib = 0; ib < EDIM / 4; ++ib) {
    const float4 w0 = *(const float4*)(WT + (4 * ib + 0) * EDIM + col0);
    const float4 w1 = *(const float4*)(WT + (4 * ib + 1) * EDIM + col0);
    const float4 w2 = *(const float4*)(WT + (4 * ib + 2) * EDIM + col0);
    const float4 w3 = *(const float4*)(WT + (4 * ib + 3) * EDIM + col0);
    #pragma unroll
    for (int r = 0; r < 4; ++r) {
      const float4 x4 = *(const float4*)(&xs[tr * 4 + r][ib * 4]);  // b128 broadcast
      acc[r][0] += x4.x * w0.x + x4.y * w1.x + x4.z * w2.x + x4.w * w3.x;
      acc[r][1] += x4.x * w0.y + x4.y * w1.y + x4.z * w2.y + x4.w * w3.y;
      acc[r][2] += x4.x * w0.z + x4.y * w1.z + x4.z * w2.z + x4.w * w3.z;
      acc[r][3] += x4.x * w0.w + x4.y * w1.w + x4.z * w2.w + x4.w * w3.w;
    }
  }

  const float4 b4 = *(const float4*)(bias + col0);
  #pragma unroll
  for (int r = 0; r < 4; ++r) {
    const int grow = row0 + tr * 4 + r;
    const float4 o = make_float4(acc[r][0] + b4.x, acc[r][1] + b4.y,
                                 acc[r][2] + b4.z, acc[r][3] + b4.w);
    if (mode == 3) {
      *(float4*)((float*)out + (size_t)grow * EDIM + col0) = o;
    } else {
      const int b = grow >> 11, s = grow & (SEQ - 1);
      const int h = col0 >> 3, d0 = col0 & 7;     // d0 in {0,4}
      const size_t bhs = (size_t)(b * NHEAD + h) * SEQ + s;
      uint2 p;
      if (mode == 0) {
        p.x = pk_bf16(o.x * QNEG, o.y * QNEG);
        p.y = pk_bf16(o.z * QNEG, o.w * QNEG);
      } else {
        p.x = pk_bf16(o.x, o.y);
        p.y = pk_bf16(o.z, o.w);
      }
      *(uint2*)((unsigned*)out + bhs * 4 + (d0 >> 1)) = p;
    }
  }
}

__global__ __launch_bounds__(256)
void qkv_kernel(const float* __restrict__ X, const float* __restrict__ WT,
                const float* __restrict__ bq, const float* __restrict__ bk,
                const float* __restrict__ bv,
                unsigned* __restrict__ qb, unsigned* __restrict__ kb,
                unsigned* __restrict__ vb)
{
  const int m = blockIdx.y;
  const float* wt   = WT + m * EDIM * EDIM;
  const float* bias = (m == 0) ? bq : (m == 1) ? bk : bv;
  void* out         = (m == 0) ? (void*)qb : (m == 1) ? (void*)kb : (void*)vb;
  proj_body(X, wt, bias, out, m);
}

__global__ __launch_bounds__(256)
void oproj_kernel(const float* __restrict__ A, const float* __restrict__ WTo,
                  const float* __restrict__ bo, float* __restrict__ out)
{
  proj_body(A, WTo, bo, (void*)out, 3);
}

// ---------------------------------------------------------------------------
// One 16q x 16k MFMA step.
// S^T = mfma_16x16x32_bf16(A=K-rows, B=Q-frag) -> C[key][q] (row=4*quad+reg,
// col=laneq). Sigmoid elementwise. The C-register reinterpreted as an
// A-operand of mfma_16x16x16 reads A[m=laneq][k=4*quad+j] = S[q][key]: the
// UN-transposed scores. So out[q][d] = mfma(A=P, B=V-frag, acc) directly.
// V-frag B[k=4*quad+j][n=laneq] = V[16t+4q+j][laneq]; col n=8 is forced to
// 1.0 so acc col 8 accumulates the denominator. Cols 9..15 are junk
// (never stored).
// ---------------------------------------------------------------------------
template<bool DIAG>
__device__ __forceinline__
float4v attn_step(short8v kf, short8v qf, short4v vf, float4v acc,
                  int laneq, int quad)
{
  const float4v z = {0.f, 0.f, 0.f, 0.f};
  float4v st = __builtin_amdgcn_mfma_f32_16x16x32_bf16(kf, qf, z, 0, 0, 0);
  unsigned rb[4];
  #pragma unroll
  for (int r = 0; r < 4; ++r) {
    float s = RCPF(1.f + EXP2F(st[r]));           // Q carries -scale*log2e
    if (DIAG) s = (4 * quad + r <= laneq) ? s : 0.f;  // exact: sigma(-1e9)==0
    rb[r] = __float_as_uint(s) + 0x8000u;         // round-half-up to bf16
  }
  U16x4 p;
  p.u.x = __builtin_amdgcn_perm(rb[1], rb[0], 0x07060302u);
  p.u.y = __builtin_amdgcn_perm(rb[3], rb[2], 0x07060302u);
  return MFMA_PV(p.s, vf, acc);                   // A = P[q][k], B = V[k][d]
}

// V-frag loader: 4 u16 loads from V[bh][s][8]; lanes laneq==8 -> bf16 1.0
__device__ __forceinline__
short4v load_vfrag(const unsigned short* __restrict__ Vbh, int t,
                   int quad, int d, bool is8)
{
  const int s0 = 16 * t + 4 * quad;
  const unsigned v0 = Vbh[(s0 + 0) * 8 + d];
  const unsigned v1 = Vbh[(s0 + 1) * 8 + d];
  const unsigned v2 = Vbh[(s0 + 2) * 8 + d];
  const unsigned v3 = Vbh[(s0 + 3) * 8 + d];
  U16x4 vf;
  vf.u.x = is8 ? 0x3F803F80u : (v0 | (v1 << 16));
  vf.u.y = is8 ? 0x3F803F80u : (v2 | (v3 << 16));
  return vf.s;
}

// epilogue: den = acc col 8; normalize and store rows of tile T
__device__ __forceinline__
void epilogue(float4v acc, int T, int bh, int laneq, int quad,
              float* __restrict__ out)
{
  const int b_ = bh >> 4, h = bh & 15;
  const int pidx = (quad * 16 + 8) << 2;          // lane holding col 8
  #pragma unroll
  for (int r = 0; r < 4; ++r) {
    const float den = __int_as_float(
        __builtin_amdgcn_ds_bpermute(pidx, __float_as_int(acc[r])));
    const float val = acc[r] * RCPF(den);         // den > 0
    const int row = 16 * T + 4 * quad + r;
    if (laneq < 8)
      out[(size_t)(b_ * SEQ + row) * EDIM + h * HDIM + laneq] = val;
  }
}

// ---------------------------------------------------------------------------
// Causal sigmoid-attention v8: split-K x2, 100%-occupancy target.
// Fold-pair (L=g, H=127-g) = 129 key-tile steps, split between 2 waves of a
// 128-thr block: wave0 takes k-tiles [0,mL) for L and [0,mH) for H (dual
// chains share k/v frags, no diags); wave1 takes [mL,L] and [mH,H] (both
// diag steps). ~64.5 steps each, all blocks identical -> perfect balance.
// 8192 waves = 8/SIMD. Zero hot-loop LDS; 2 KB combine + 1 barrier.
// blockIdx low 6 bits = bh -> XCD = bh%8 (L2 locality).
// ---------------------------------------------------------------------------
__global__ __launch_bounds__(128, 8)
void attn_kernel(const unsigned* __restrict__ Qb, const unsigned* __restrict__ Kb,
                 const unsigned* __restrict__ Vb, float* __restrict__ out)
{
  __shared__ float cmb[2][64][4];                 // 2 KB

  const int bh    = blockIdx.x & 63;
  const int g     = blockIdx.x >> 6;              // 0..63
  const int w     = threadIdx.x >> 6;
  const int lane  = threadIdx.x & 63;
  const int laneq = lane & 15;
  const int quad  = lane >> 4;
  const int L = g, H = 127 - g;
  const int mL = (L + 1) >> 1, mH = (H + 1) >> 1;
  const int d   = laneq & 7;
  const bool is8 = (laneq == 8);

  const uint4* Kg = (const uint4*)Kb + (size_t)bh * 2048;
  const uint4* Qg = (const uint4*)Qb + (size_t)bh * 2048;
  const unsigned short* Vbh = (const unsigned short*)Vb + (size_t)bh * 2048 * 8;

  // Q B-frags: lanes<16 hold the 8-dim row in quad 0 (k=0..7); zero others
  U16x8 qfl, qfh;
  {
    const uint4 rl = Qg[16 * L + laneq];
    const uint4 rh = Qg[16 * H + laneq];
    qfl.u = (lane < 16) ? rl : make_uint4(0u, 0u, 0u, 0u);
    qfh.u = (lane < 16) ? rh : make_uint4(0u, 0u, 0u, 0u);
  }

  float4v accL = {0.f, 0.f, 0.f, 0.f};
  float4v accH = {0.f, 0.f, 0.f, 0.f};

  if (w == 0) {
    // k-tiles [0,mL) dual (L+H), [mL,mH) H-only; no diags; prefetch 1 deep
    U16x8 kf; kf.u = Kg[laneq];
    short4v vf = load_vfrag(Vbh, 0, quad, d, is8);
    #pragma unroll 2
    for (int t = 0; t < mH; ++t) {
      U16x8 kn; kn.u = Kg[16 * (t + 1) + laneq];  // t+1 <= mH <= 64: in-bounds
      short4v vn = load_vfrag(Vbh, t + 1, quad, d, is8);
      if (t < mL) accL = attn_step<false>(kf.s, qfl.s, vf, accL, laneq, quad);
      accH = attn_step<false>(kf.s, qfh.s, vf, accH, laneq, quad);
      kf = kn; vf = vn;
    }
  } else {
    // L segment: [mL, L], diag at L
    U16x8 kf; kf.u = Kg[16 * mL + laneq];
    short4v vf = load_vfrag(Vbh, mL, quad, d, is8);
    #pragma unroll 2
    for (int t = mL; t < L; ++t) {
      U16x8 kn; kn.u = Kg[16 * (t + 1) + laneq];
      short4v vn = load_vfrag(Vbh, t + 1, quad, d, is8);
      accL = attn_step<false>(kf.s, qfl.s, vf, accL, laneq, quad);
      kf = kn; vf = vn;
    }
    accL = attn_step<true>(kf.s, qfl.s, vf, accL, laneq, quad);
    // H segment: [mH, H], diag at H
    kf.u = Kg[16 * mH + laneq];
    vf = load_vfrag(Vbh, mH, quad, d, is8);
    #pragma unroll 2
    for (int t = mH; t < H; ++t) {
      U16x8 kn; kn.u = Kg[16 * (t + 1) + laneq];  // t+1 <= H = 127: in-bounds
      short4v vn = load_vfrag(Vbh, t + 1, quad, d, is8);
      accH = attn_step<false>(kf.s, qfh.s, vf, accH, laneq, quad);
      kf = kn; vf = vn;
    }
    accH = attn_step<true>(kf.s, qfh.s, vf, accH, laneq, quad);

    *(float4*)&cmb[0][lane][0] = make_float4(accL[0], accL[1], accL[2], accL[3]);
    *(float4*)&cmb[1][lane][0] = make_float4(accH[0], accH[1], accH[2], accH[3]);
  }
  __syncthreads();

  if (w == 0) {
    const float4 pL = *(const float4*)&cmb[0][lane][0];
    const float4 pH = *(const float4*)&cmb[1][lane][0];
    accL[0] += pL.x; accL[1] += pL.y; accL[2] += pL.z; accL[3] += pL.w;
    accH[0] += pH.x; accH[1] += pH.y; accH[2] += pH.z; accH[3] += pH.w;
    epilogue(accL, L, bh, laneq, quad, out);
    epilogue(accH, H, bh, laneq, quad, out);
  }
}

// ---------------------------------------------------------------------------
extern "C" void kernel_launch(void* const* d_in, const int* in_sizes, int n_in,
                              void* d_out, int out_size, void* d_ws, size_t ws_size,
                              hipStream_t stream)
{
  const float* x  = (const float*)d_in[0];
  const float* Wq = (const float*)d_in[1];
  const float* bq = (const float*)d_in[2];
  const float* Wk = (const float*)d_in[3];
  const float* bk = (const float*)d_in[4];
  const float* Wv = (const float*)d_in[5];
  const float* bv = (const float*)d_in[6];
  const float* Wo = (const float*)d_in[7];
  const float* bo = (const float*)d_in[8];

  float* ws = (float*)d_ws;
  // layout: WT 65536 f | attn 1048576 f | Qb, Kb, Vb 524288 dwords each
  float*    WT   = ws;
  float*    attn = ws + 65536;
  unsigned* Qb   = (unsigned*)(ws + 65536 + 1048576);
  unsigned* Kb   = Qb + (size_t)524288;
  unsigned* Vb   = Kb + (size_t)524288;

  transpose4_kernel<<<dim3(8, 4), 256, 0, stream>>>(Wq, Wk, Wv, Wo, WT);
  qkv_kernel<<<dim3(NROW / 32, 3), 256, 0, stream>>>(x, WT, bq, bk, bv, Qb, Kb, Vb);
  attn_kernel<<<dim3(4096), 128, 0, stream>>>(Qb, Kb, Vb, attn);
  oproj_kernel<<<dim3(NROW / 32), 256, 0, stream>>>(attn, WT + 3 * EDIM * EDIM, bo,
                                                    (float*)d_out);
}